// Round 4
// baseline (8152.698 us; speedup 1.0000x reference)
//
#include <hip/hip_runtime.h>
#include <stdint.h>

#define TT 512
#define BB 64
#define II 512
#define HH 1024

typedef __attribute__((ext_vector_type(8))) _Float16 half8;
typedef __attribute__((ext_vector_type(4))) float f32x4;

__device__ __forceinline__ float fsig(float x)  { return 1.0f / (1.0f + __expf(-x)); }
__device__ __forceinline__ float ftanh(float x) { return 1.0f - 2.0f / (1.0f + __expf(2.0f * x)); }

// ws: 4 batch-groups x dbuf x [16][HH] f32 h words; low 3 bits of each word = step tag.
// tag(t) = 1 + (t & 3) in {1,2,3,4}; init 0 never matches; t vs t-2 tags always differ.
#define ZWORDS (4 * 2 * 16 * HH)

__global__ void lstm_init(uint32_t* ws) {
  const uint32_t i = blockIdx.x * 256u + threadIdx.x;
  if (i < ZWORDS) ws[i] = 0u;
}

// Persistent LSTM: 128 WGs = 2 chain-pairs x 64 col-groups. Each WG interleaves TWO
// independent batch-group chains (A = 2*pc, B = 2*pc+1) per timestep, reusing the SAME
// VGPR-resident weight fragments (weights depend only on col-group). The B-phase compute
// (~2us) sits between peers' A-publish(t-1) and my A-poll(t), hiding the one-way L3
// latency + skew that round 3 paid serially every step. Per-chain sync protocol is
// unchanged from round 3 (self-validating tagged words, incremental polling).
__global__ __launch_bounds__(256, 1)
void lstm_persist(const float* __restrict__ x,
                  const float* __restrict__ wii, const float* __restrict__ bii,
                  const float* __restrict__ wif_, const float* __restrict__ bif_,
                  const float* __restrict__ wig, const float* __restrict__ big_,
                  const float* __restrict__ wio, const float* __restrict__ bio,
                  const float* __restrict__ whi, const float* __restrict__ bhi,
                  const float* __restrict__ whf, const float* __restrict__ bhf,
                  const float* __restrict__ whg, const float* __restrict__ bhg,
                  const float* __restrict__ who, const float* __restrict__ bho,
                  float* __restrict__ out, uint8_t* __restrict__ ws)
{
  const int tid  = threadIdx.x;
  const int wid  = tid >> 6;      // wave 0..3 : K-split (K = 1536 = 512 x + 1024 h)
  const int lane = tid & 63;
  const int quad = lane >> 4;
  const int lrow = lane & 15;

  const int wg   = blockIdx.x;
  const int pc   = wg >> 6;       // chain pair 0..1
  const int gc   = wg & 63;       // col group 0..63
  const int col0 = gc << 4;
  const int gbA  = pc * 2,      gbB  = pc * 2 + 1;
  const int b0A  = gbA << 4,    b0B  = gbB << 4;

  const float* wi[4] = {wii, wif_, wig, wio};
  const float* wh[4] = {whi, whf, whg, who};
  const float* bi[4] = {bii, bif_, big_, bio};
  const float* bh[4] = {bhi, bhf, bhg, bho};

  uint32_t* zgA = (uint32_t*)ws + gbA * (2 * 16 * HH);
  uint32_t* zgB = (uint32_t*)ws + gbB * (2 * 16 * HH);

  // ---- persistent weight fragments (B operand: B[k][n], n=lane&15, k=quad*8+j) ----
  const int kb = wid * 384;       // this wave's K-range in concatenated K=[x(512); h(1024)]
  half8 wfrag[12][4];
#pragma unroll
  for (int kk = 0; kk < 12; ++kk) {
    const int k = kb + kk * 32 + quad * 8;
#pragma unroll
    for (int g = 0; g < 4; ++g) {
      const float* wp = (k < II) ? (wi[g] + (size_t)(col0 + lrow) * II + k)
                                 : (wh[g] + (size_t)(col0 + lrow) * HH + (k - II));
      half8 v;
#pragma unroll
      for (int j = 0; j < 8; ++j) v[j] = (_Float16)wp[j];
      wfrag[kk][g] = v;
    }
  }

  // per-thread elementwise ownership: (tb, thc) = one (batch-in-group, h-col) cell
  const int tb   = tid >> 4;
  const int thc  = tid & 15;
  const int gcol = col0 + thc;
  float bias[4];
#pragma unroll
  for (int g = 0; g < 4; ++g) bias[g] = bi[g][gcol] + bh[g][gcol];

  float cA = 0.0f, hA = 0.0f, cB = 0.0f, hB = 0.0f;

  __shared__ float red[2][16 * 288];  // one buffer per phase; phase barrier separates reuse

  // one chain-step: poll h(t-1), GEMM, cross-wave reduce, elementwise, publish h(t)
  auto phase = [&](int t, int b0, uint32_t* zgc, float& cs, float& hs, float* redb) {
    const uint32_t* zp   = zgc + (t & 1) * (16 * HH);
    uint32_t*       zn   = zgc + ((t + 1) & 1) * (16 * HH);
    const float*    xrow = x + ((size_t)t * BB + b0 + lrow) * II;
    const uint32_t* zrow = zp + lrow * HH;

    // A frags: A[m=lane&15][k=quad*8+j]; k<512 from x (L2-cached fp32)
    half8 af[12];
#pragma unroll
    for (int kk = 0; kk < 12; ++kk) {
      const int k = kb + kk * 32 + quad * 8;
      if (kb + kk * 32 < II) {
        f32x4 v0 = *(const f32x4*)(xrow + k);
        f32x4 v1 = *(const f32x4*)(xrow + k + 4);
        half8 v;
#pragma unroll
        for (int j = 0; j < 4; ++j) { v[j] = (_Float16)v0[j]; v[4 + j] = (_Float16)v1[j]; }
        af[kk] = v;
      }
    }

    // h-part: incremental tag-polled loads. A word carrying the current tag IS the data;
    // lanes clear frags from `pend` as they turn fresh and only re-load stale ones.
    if (t == 0) {
#pragma unroll
      for (int kk = 0; kk < 12; ++kk)
        if (kb + kk * 32 >= II) {
          half8 v;
#pragma unroll
          for (int j = 0; j < 8; ++j) v[j] = (_Float16)0.0f;
          af[kk] = v;
        }
    } else if (wid > 0) {
      const uint32_t etag = 1u + ((t - 1) & 3u);
      uint32_t pend = 0u;
#pragma unroll
      for (int kk = 0; kk < 12; ++kk)
        if (kb + kk * 32 >= II) pend |= 1u << kk;
      int guard = 0;
      for (;;) {
#pragma unroll
        for (int kk = 0; kk < 12; ++kk) {
          if (kb + kk * 32 < II) continue;           // wave-uniform skip
          if (pend & (1u << kk)) {                   // per-lane: only stale frags
            const int k = kb + kk * 32 + quad * 8;
            const uint64_t* p = (const uint64_t*)(zrow + (k - II));
            union { uint64_t q[4]; uint32_t u[8]; } cv;
            cv.q[0] = __hip_atomic_load(p + 0, __ATOMIC_RELAXED, __HIP_MEMORY_SCOPE_AGENT);
            cv.q[1] = __hip_atomic_load(p + 1, __ATOMIC_RELAXED, __HIP_MEMORY_SCOPE_AGENT);
            cv.q[2] = __hip_atomic_load(p + 2, __ATOMIC_RELAXED, __HIP_MEMORY_SCOPE_AGENT);
            cv.q[3] = __hip_atomic_load(p + 3, __ATOMIC_RELAXED, __HIP_MEMORY_SCOPE_AGENT);
            uint32_t bad = 0u;
#pragma unroll
            for (int j = 0; j < 8; ++j) bad |= (cv.u[j] ^ etag) & 7u;
            if (bad == 0u) {
              half8 v;
#pragma unroll
              for (int j = 0; j < 8; ++j)
                v[j] = (_Float16)__uint_as_float(cv.u[j]);  // tag bits: <=2^-20 rel noise
              af[kk] = v;
              pend &= ~(1u << kk);
            }
          }
        }
        if (__all(pend == 0u)) break;
        if (++guard > (1 << 18)) break;              // fail loud, not hang
        __builtin_amdgcn_s_sleep(1);
      }
    }

    f32x4 acc[4];
#pragma unroll
    for (int g = 0; g < 4; ++g) acc[g] = (f32x4){0.f, 0.f, 0.f, 0.f};
#pragma unroll
    for (int kk = 0; kk < 12; ++kk)
#pragma unroll
      for (int g = 0; g < 4; ++g)
        acc[g] = __builtin_amdgcn_mfma_f32_16x16x32_f16(af[kk], wfrag[kk][g], acc[g], 0, 0, 0);

    // cross-wave K reduction via LDS; D layout: row(m)=quad*4+r, col(n)=lane&15
#pragma unroll
    for (int g = 0; g < 4; ++g)
#pragma unroll
      for (int r = 0; r < 4; ++r)
        redb[(wid * 4 + g) * 288 + quad * 72 + r * 16 + lrow] = acc[g][r];
    __syncthreads();   // one barrier per phase; prev-phase stores are ~a phase old

    float pre[4];
#pragma unroll
    for (int g = 0; g < 4; ++g) {
      float s = bias[g];
#pragma unroll
      for (int w = 0; w < 4; ++w)
        s += redb[(w * 4 + g) * 288 + (tb >> 2) * 72 + (tb & 3) * 16 + thc];
      pre[g] = s;
    }

    const float it = fsig(pre[0]);
    const float ft = fsig(pre[1]);
    const float gt = ftanh(pre[2]);
    const float ot = fsig(pre[3]);
    cs = ft * cs + it * gt;
    hs = ot * ftanh(cs);

    // publish FIRST (starts the one-way L3 trip), then the HBM out-store.
    if (t < TT - 1) {
      const uint32_t stag = 1u + (t & 3u);
      __hip_atomic_store(zn + tb * HH + gcol, (__float_as_uint(hs) & ~7u) | stag,
                         __ATOMIC_RELAXED, __HIP_MEMORY_SCOPE_AGENT);
    }
    out[((size_t)t * BB + b0 + tb) * HH + gcol] = hs;
  };

#pragma unroll 1
  for (int t = 0; t < TT; ++t) {
    phase(t, b0A, zgA, cA, hA, red[0]);
    phase(t, b0B, zgB, cB, hB, red[1]);
  }

  // tails: h_T then c_T, each [B][H]
  out[(size_t)TT * BB * HH + (size_t)(b0A + tb) * HH + gcol] = hA;
  out[(size_t)TT * BB * HH + (size_t)BB * HH + (size_t)(b0A + tb) * HH + gcol] = cA;
  out[(size_t)TT * BB * HH + (size_t)(b0B + tb) * HH + gcol] = hB;
  out[(size_t)TT * BB * HH + (size_t)BB * HH + (size_t)(b0B + tb) * HH + gcol] = cB;
}

extern "C" void kernel_launch(void* const* d_in, const int* in_sizes, int n_in,
                              void* d_out, int out_size, void* d_ws, size_t ws_size,
                              hipStream_t stream) {
  const float* x    = (const float*)d_in[0];
  const float* wii  = (const float*)d_in[1];
  const float* bii  = (const float*)d_in[2];
  const float* wif_ = (const float*)d_in[3];
  const float* bif_ = (const float*)d_in[4];
  const float* wig  = (const float*)d_in[5];
  const float* big_ = (const float*)d_in[6];
  const float* wio  = (const float*)d_in[7];
  const float* bio  = (const float*)d_in[8];
  const float* whi  = (const float*)d_in[9];
  const float* bhi  = (const float*)d_in[10];
  const float* whf  = (const float*)d_in[11];
  const float* bhf  = (const float*)d_in[12];
  const float* whg  = (const float*)d_in[13];
  const float* bhg  = (const float*)d_in[14];
  const float* who  = (const float*)d_in[15];
  const float* bho  = (const float*)d_in[16];

  lstm_init<<<(ZWORDS + 255) / 256, 256, 0, stream>>>((uint32_t*)d_ws);
  lstm_persist<<<128, 256, 0, stream>>>(x, wii, bii, wif_, bif_, wig, big_, wio, bio,
                                        whi, bhi, whf, bhf, whg, bhg, who, bho,
                                        (float*)d_out, (uint8_t*)d_ws);
}

// Round 5
// 5163.990 us; speedup vs baseline: 1.5788x; 1.5788x over previous
//
#include <hip/hip_runtime.h>
#include <stdint.h>

#define TT 512
#define BB 64
#define II 512
#define HH 1024

typedef __attribute__((ext_vector_type(8))) _Float16 half8;
typedef __attribute__((ext_vector_type(4))) float f32x4;

__device__ __forceinline__ float fsig(float x)  { return 1.0f / (1.0f + __expf(-x)); }
__device__ __forceinline__ float ftanh(float x) { return 1.0f - 2.0f / (1.0f + __expf(2.0f * x)); }

// ws: 4 batch-groups x dbuf x [16][HH] f32 h words; low 3 bits of each word = step tag.
// tag(t) = 1 + (t & 3) in {1,2,3,4}; init 0 never matches; t vs t-2 tags always differ.
#define ZWORDS (4 * 2 * 16 * HH)

__global__ void lstm_init(uint32_t* ws) {
  const uint32_t i = blockIdx.x * 256u + threadIdx.x;
  if (i < ZWORDS) ws[i] = 0u;
}

// Persistent LSTM: 256 WGs = 4 batch-groups (16 batches) x 64 col-groups (16 h-cols x 4 gates).
// Weights live in VGPRs/AGPRs as fp16 MFMA B-frags. Cross-WG h exchange: self-validating
// tagged f32 words through L3 (relaxed agent atomics). Round-5 change: the h-poll is split
// into ISSUE-ALL (raw bits, no uses -> all loads in flight concurrently, ONE latency) then
// CHECK+CONVERT, then INCREMENTAL RETRY of stale frags only. Rounds 0-4 paid the uncached
// load latency ~12x serially per step because each frag's tag-check forced a waitcnt.
__global__ __launch_bounds__(256, 1)
void lstm_persist(const float* __restrict__ x,
                  const float* __restrict__ wii, const float* __restrict__ bii,
                  const float* __restrict__ wif_, const float* __restrict__ bif_,
                  const float* __restrict__ wig, const float* __restrict__ big_,
                  const float* __restrict__ wio, const float* __restrict__ bio,
                  const float* __restrict__ whi, const float* __restrict__ bhi,
                  const float* __restrict__ whf, const float* __restrict__ bhf,
                  const float* __restrict__ whg, const float* __restrict__ bhg,
                  const float* __restrict__ who, const float* __restrict__ bho,
                  float* __restrict__ out, uint8_t* __restrict__ ws)
{
  const int tid  = threadIdx.x;
  const int wid  = tid >> 6;      // wave 0..3 : K-split (K = 1536 = 512 x + 1024 h)
  const int lane = tid & 63;
  const int quad = lane >> 4;
  const int lrow = lane & 15;

  const int wg   = blockIdx.x;
  const int gb   = wg >> 6;       // batch group 0..3
  const int gc   = wg & 63;       // col group 0..63
  const int b0   = gb << 4;
  const int col0 = gc << 4;

  const float* wi[4] = {wii, wif_, wig, wio};
  const float* wh[4] = {whi, whf, whg, who};
  const float* bi[4] = {bii, bif_, big_, bio};
  const float* bh[4] = {bhi, bhf, bhg, bho};

  uint32_t* zg = (uint32_t*)ws + gb * (2 * 16 * HH);  // this group's tagged-h buffers

  // ---- persistent weight fragments (B operand: B[k][n], n=lane&15, k=quad*8+j) ----
  const int kb = wid * 384;       // this wave's K-range in concatenated K=[x(512); h(1024)]
  half8 wfrag[12][4];
#pragma unroll
  for (int kk = 0; kk < 12; ++kk) {
    const int k = kb + kk * 32 + quad * 8;
#pragma unroll
    for (int g = 0; g < 4; ++g) {
      const float* wp = (k < II) ? (wi[g] + (size_t)(col0 + lrow) * II + k)
                                 : (wh[g] + (size_t)(col0 + lrow) * HH + (k - II));
      half8 v;
#pragma unroll
      for (int j = 0; j < 8; ++j) v[j] = (_Float16)wp[j];
      wfrag[kk][g] = v;
    }
  }

  // wave-uniform: does this wave own any h-frags?
  const bool has_h = (kb + 11 * 32) >= II;

  // per-thread elementwise ownership: (tb, thc) = one (batch, h-col) cell
  const int tb   = tid >> 4;
  const int thc  = tid & 15;
  const int gcol = col0 + thc;
  float bias[4];
#pragma unroll
  for (int g = 0; g < 4; ++g) bias[g] = bi[g][gcol] + bh[g][gcol];

  float c = 0.0f, h = 0.0f;

  __shared__ float red[2][16 * 288];  // double-buffered -> no end-of-step barrier

#pragma unroll 1
  for (int t = 0; t < TT; ++t) {
    const uint32_t* zp   = zg + (t & 1) * (16 * HH);
    uint32_t*       zn   = zg + ((t + 1) & 1) * (16 * HH);
    const float*    xrow = x + ((size_t)t * BB + b0 + lrow) * II;
    const uint32_t* zrow = zp + lrow * HH;

    // A frags: A[m=lane&15][k=quad*8+j]; k<512 from x (L2/L3-cached fp32)
    half8 af[12];
#pragma unroll
    for (int kk = 0; kk < 12; ++kk) {
      const int k = kb + kk * 32 + quad * 8;
      if (kb + kk * 32 < II) {
        f32x4 v0 = *(const f32x4*)(xrow + k);
        f32x4 v1 = *(const f32x4*)(xrow + k + 4);
        half8 v;
#pragma unroll
        for (int j = 0; j < 4; ++j) { v[j] = (_Float16)v0[j]; v[4 + j] = (_Float16)v1[j]; }
        af[kk] = v;
      }
    }

    // ---- h-part: parallel-issue tag-polled loads ----
    if (t == 0) {
#pragma unroll
      for (int kk = 0; kk < 12; ++kk)
        if (kb + kk * 32 >= II) {
          half8 v;
#pragma unroll
          for (int j = 0; j < 8; ++j) v[j] = (_Float16)0.0f;
          af[kk] = v;
        }
    } else if (has_h) {
      const uint32_t etag = 1u + ((t - 1) & 3u);
      union Cv { uint64_t q[4]; uint32_t u[8]; };
      Cv cv[12];

      // stage 1: ISSUE all loads -- no value uses between them, so every load of every
      // frag is in flight concurrently and the whole pass costs ~one uncached latency.
#pragma unroll
      for (int kk = 0; kk < 12; ++kk) {
        if (kb + kk * 32 < II) continue;             // wave-uniform
        const int k = kb + kk * 32 + quad * 8;
        const uint64_t* p = (const uint64_t*)(zrow + (k - II));
        cv[kk].q[0] = __hip_atomic_load(p + 0, __ATOMIC_RELAXED, __HIP_MEMORY_SCOPE_AGENT);
        cv[kk].q[1] = __hip_atomic_load(p + 1, __ATOMIC_RELAXED, __HIP_MEMORY_SCOPE_AGENT);
        cv[kk].q[2] = __hip_atomic_load(p + 2, __ATOMIC_RELAXED, __HIP_MEMORY_SCOPE_AGENT);
        cv[kk].q[3] = __hip_atomic_load(p + 3, __ATOMIC_RELAXED, __HIP_MEMORY_SCOPE_AGENT);
      }

      // stage 2: check tags + convert; build pending mask
      uint32_t pend = 0u;
#pragma unroll
      for (int kk = 0; kk < 12; ++kk) {
        if (kb + kk * 32 < II) continue;
        uint32_t bad = 0u;
#pragma unroll
        for (int j = 0; j < 8; ++j) bad |= (cv[kk].u[j] ^ etag) & 7u;
        half8 v;
#pragma unroll
        for (int j = 0; j < 8; ++j)
          v[j] = (_Float16)__uint_as_float(cv[kk].u[j]);  // tag bits: <=2^-20 rel noise
        af[kk] = v;
        pend |= bad ? (1u << kk) : 0u;
      }

      // stage 3: incremental retry of stale frags only (rare straggler path)
      int guard = 0;
      while (!__all(pend == 0u)) {
        if (++guard > (1 << 18)) break;              // fail loud, not hang
        __builtin_amdgcn_s_sleep(1);
#pragma unroll
        for (int kk = 0; kk < 12; ++kk) {
          if (kb + kk * 32 < II) continue;
          if (pend & (1u << kk)) {
            const int k = kb + kk * 32 + quad * 8;
            const uint64_t* p = (const uint64_t*)(zrow + (k - II));
            Cv c2;
            c2.q[0] = __hip_atomic_load(p + 0, __ATOMIC_RELAXED, __HIP_MEMORY_SCOPE_AGENT);
            c2.q[1] = __hip_atomic_load(p + 1, __ATOMIC_RELAXED, __HIP_MEMORY_SCOPE_AGENT);
            c2.q[2] = __hip_atomic_load(p + 2, __ATOMIC_RELAXED, __HIP_MEMORY_SCOPE_AGENT);
            c2.q[3] = __hip_atomic_load(p + 3, __ATOMIC_RELAXED, __HIP_MEMORY_SCOPE_AGENT);
            uint32_t bad = 0u;
#pragma unroll
            for (int j = 0; j < 8; ++j) bad |= (c2.u[j] ^ etag) & 7u;
            if (bad == 0u) {
              half8 v;
#pragma unroll
              for (int j = 0; j < 8; ++j) v[j] = (_Float16)__uint_as_float(c2.u[j]);
              af[kk] = v;
              pend &= ~(1u << kk);
            }
          }
        }
      }
    }

    f32x4 acc[4];
#pragma unroll
    for (int g = 0; g < 4; ++g) acc[g] = (f32x4){0.f, 0.f, 0.f, 0.f};
#pragma unroll
    for (int kk = 0; kk < 12; ++kk)
#pragma unroll
      for (int g = 0; g < 4; ++g)
        acc[g] = __builtin_amdgcn_mfma_f32_16x16x32_f16(af[kk], wfrag[kk][g], acc[g], 0, 0, 0);

    // cross-wave K reduction via LDS; D layout: row(m)=quad*4+r, col(n)=lane&15
    float* redb = red[t & 1];
#pragma unroll
    for (int g = 0; g < 4; ++g)
#pragma unroll
      for (int r = 0; r < 4; ++r)
        redb[(wid * 4 + g) * 288 + quad * 72 + r * 16 + lrow] = acc[g][r];
    __syncthreads();   // only barrier per step; all outstanding vmem is a step old

    float pre[4];
#pragma unroll
    for (int g = 0; g < 4; ++g) {
      float s = bias[g];
#pragma unroll
      for (int w = 0; w < 4; ++w)
        s += redb[(w * 4 + g) * 288 + (tb >> 2) * 72 + (tb & 3) * 16 + thc];
      pre[g] = s;
    }

    const float it = fsig(pre[0]);
    const float ft = fsig(pre[1]);
    const float gt = ftanh(pre[2]);
    const float ot = fsig(pre[3]);
    c = ft * c + it * gt;
    h = ot * ftanh(c);

    // publish FIRST (starts the one-way L3 trip), then the HBM out-store.
    if (t < TT - 1) {
      const uint32_t stag = 1u + (t & 3u);
      __hip_atomic_store(zn + tb * HH + gcol, (__float_as_uint(h) & ~7u) | stag,
                         __ATOMIC_RELAXED, __HIP_MEMORY_SCOPE_AGENT);
    }
    out[((size_t)t * BB + b0 + tb) * HH + gcol] = h;
  }

  // tails: h_T then c_T, each [B][H]
  out[(size_t)TT * BB * HH + (size_t)(b0 + tb) * HH + gcol] = h;
  out[(size_t)TT * BB * HH + (size_t)BB * HH + (size_t)(b0 + tb) * HH + gcol] = c;
}

extern "C" void kernel_launch(void* const* d_in, const int* in_sizes, int n_in,
                              void* d_out, int out_size, void* d_ws, size_t ws_size,
                              hipStream_t stream) {
  const float* x    = (const float*)d_in[0];
  const float* wii  = (const float*)d_in[1];
  const float* bii  = (const float*)d_in[2];
  const float* wif_ = (const float*)d_in[3];
  const float* bif_ = (const float*)d_in[4];
  const float* wig  = (const float*)d_in[5];
  const float* big_ = (const float*)d_in[6];
  const float* wio  = (const float*)d_in[7];
  const float* bio  = (const float*)d_in[8];
  const float* whi  = (const float*)d_in[9];
  const float* bhi  = (const float*)d_in[10];
  const float* whf  = (const float*)d_in[11];
  const float* bhf  = (const float*)d_in[12];
  const float* whg  = (const float*)d_in[13];
  const float* bhg  = (const float*)d_in[14];
  const float* who  = (const float*)d_in[15];
  const float* bho  = (const float*)d_in[16];

  lstm_init<<<(ZWORDS + 255) / 256, 256, 0, stream>>>((uint32_t*)d_ws);
  lstm_persist<<<256, 256, 0, stream>>>(x, wii, bii, wif_, bif_, wig, big_, wio, bio,
                                        whi, bhi, whf, bhf, whg, bhg, who, bho,
                                        (float*)d_out, (uint8_t*)d_ws);
}

// Round 6
// 4590.263 us; speedup vs baseline: 1.7761x; 1.1250x over previous
//
#include <hip/hip_runtime.h>
#include <stdint.h>

#define TT 512
#define BB 64
#define II 512
#define HH 1024

typedef __attribute__((ext_vector_type(8))) _Float16 half8;
typedef __attribute__((ext_vector_type(4))) float f32x4;
typedef __attribute__((ext_vector_type(4))) uint32_t u32x4;

__device__ __forceinline__ float fsig(float x)  { return 1.0f / (1.0f + __expf(-x)); }
__device__ __forceinline__ float ftanh(float x) { return 1.0f - 2.0f / (1.0f + __expf(2.0f * x)); }

// ws: 4 batch-groups x dbuf x [16][HH] f32 h words; low 3 bits of each word = step tag.
// tag(t) = 1 + (t & 3) in {1,2,3,4}; init 0 never matches; t vs t-2 tags always differ.
#define ZWORDS (4 * 2 * 16 * HH)

__global__ void lstm_init(uint32_t* ws) {
  const uint32_t i = blockIdx.x * 256u + threadIdx.x;
  if (i < ZWORDS) ws[i] = 0u;
}

// One batched poll pass: N fragments (32B each) loaded as 2*N global_load_dwordx4 with
// immediate offsets off ONE address pair, all in flight concurrently, ONE s_waitcnt.
// sc0 sc1 = coherent scope (bypass stale L1/L2) -- same visibility as the agent-scope
// atomic loads used in rounds 2-5; per-4B-word atomicity is inherent to aligned loads,
// which is all the tag-in-word protocol needs. Early-clobber outputs force the register
// allocator to keep all destinations live (the compiler-defeating pattern of R5).
#define ZP12(c, hb)                                                      \
  asm volatile(                                                          \
    "global_load_dwordx4 %0, %24, off sc0 sc1\n\t"                       \
    "global_load_dwordx4 %1, %24, off offset:16 sc0 sc1\n\t"             \
    "global_load_dwordx4 %2, %24, off offset:128 sc0 sc1\n\t"            \
    "global_load_dwordx4 %3, %24, off offset:144 sc0 sc1\n\t"            \
    "global_load_dwordx4 %4, %24, off offset:256 sc0 sc1\n\t"            \
    "global_load_dwordx4 %5, %24, off offset:272 sc0 sc1\n\t"            \
    "global_load_dwordx4 %6, %24, off offset:384 sc0 sc1\n\t"            \
    "global_load_dwordx4 %7, %24, off offset:400 sc0 sc1\n\t"            \
    "global_load_dwordx4 %8, %24, off offset:512 sc0 sc1\n\t"            \
    "global_load_dwordx4 %9, %24, off offset:528 sc0 sc1\n\t"            \
    "global_load_dwordx4 %10, %24, off offset:640 sc0 sc1\n\t"           \
    "global_load_dwordx4 %11, %24, off offset:656 sc0 sc1\n\t"           \
    "global_load_dwordx4 %12, %24, off offset:768 sc0 sc1\n\t"           \
    "global_load_dwordx4 %13, %24, off offset:784 sc0 sc1\n\t"           \
    "global_load_dwordx4 %14, %24, off offset:896 sc0 sc1\n\t"           \
    "global_load_dwordx4 %15, %24, off offset:912 sc0 sc1\n\t"           \
    "global_load_dwordx4 %16, %24, off offset:1024 sc0 sc1\n\t"          \
    "global_load_dwordx4 %17, %24, off offset:1040 sc0 sc1\n\t"          \
    "global_load_dwordx4 %18, %24, off offset:1152 sc0 sc1\n\t"          \
    "global_load_dwordx4 %19, %24, off offset:1168 sc0 sc1\n\t"          \
    "global_load_dwordx4 %20, %24, off offset:1280 sc0 sc1\n\t"          \
    "global_load_dwordx4 %21, %24, off offset:1296 sc0 sc1\n\t"          \
    "global_load_dwordx4 %22, %24, off offset:1408 sc0 sc1\n\t"          \
    "global_load_dwordx4 %23, %24, off offset:1424 sc0 sc1\n\t"          \
    "s_waitcnt vmcnt(0)"                                                 \
    : "=&v"(c[0]), "=&v"(c[1]), "=&v"(c[2]), "=&v"(c[3]),                \
      "=&v"(c[4]), "=&v"(c[5]), "=&v"(c[6]), "=&v"(c[7]),                \
      "=&v"(c[8]), "=&v"(c[9]), "=&v"(c[10]), "=&v"(c[11]),              \
      "=&v"(c[12]), "=&v"(c[13]), "=&v"(c[14]), "=&v"(c[15]),            \
      "=&v"(c[16]), "=&v"(c[17]), "=&v"(c[18]), "=&v"(c[19]),            \
      "=&v"(c[20]), "=&v"(c[21]), "=&v"(c[22]), "=&v"(c[23])             \
    : "v"(hb) : "memory")

#define ZP8(c, hb)                                                       \
  asm volatile(                                                          \
    "global_load_dwordx4 %0, %16, off sc0 sc1\n\t"                       \
    "global_load_dwordx4 %1, %16, off offset:16 sc0 sc1\n\t"             \
    "global_load_dwordx4 %2, %16, off offset:128 sc0 sc1\n\t"            \
    "global_load_dwordx4 %3, %16, off offset:144 sc0 sc1\n\t"            \
    "global_load_dwordx4 %4, %16, off offset:256 sc0 sc1\n\t"            \
    "global_load_dwordx4 %5, %16, off offset:272 sc0 sc1\n\t"            \
    "global_load_dwordx4 %6, %16, off offset:384 sc0 sc1\n\t"            \
    "global_load_dwordx4 %7, %16, off offset:400 sc0 sc1\n\t"            \
    "global_load_dwordx4 %8, %16, off offset:512 sc0 sc1\n\t"            \
    "global_load_dwordx4 %9, %16, off offset:528 sc0 sc1\n\t"            \
    "global_load_dwordx4 %10, %16, off offset:640 sc0 sc1\n\t"           \
    "global_load_dwordx4 %11, %16, off offset:656 sc0 sc1\n\t"           \
    "global_load_dwordx4 %12, %16, off offset:768 sc0 sc1\n\t"           \
    "global_load_dwordx4 %13, %16, off offset:784 sc0 sc1\n\t"           \
    "global_load_dwordx4 %14, %16, off offset:896 sc0 sc1\n\t"           \
    "global_load_dwordx4 %15, %16, off offset:912 sc0 sc1\n\t"           \
    "s_waitcnt vmcnt(0)"                                                 \
    : "=&v"(c[0]), "=&v"(c[1]), "=&v"(c[2]), "=&v"(c[3]),                \
      "=&v"(c[4]), "=&v"(c[5]), "=&v"(c[6]), "=&v"(c[7]),                \
      "=&v"(c[8]), "=&v"(c[9]), "=&v"(c[10]), "=&v"(c[11]),              \
      "=&v"(c[12]), "=&v"(c[13]), "=&v"(c[14]), "=&v"(c[15])             \
    : "v"(hb) : "memory")

// Persistent LSTM: 256 WGs = 4 batch-groups (16 batches) x 64 col-groups (16 h-cols x 4
// gates). Weights live in the unified VGPR/AGPR file as fp16 MFMA B-frags. Cross-WG h
// exchange: self-validating tagged f32 words through L3. Round-6 change: the poll pass
// is ONE asm block per wave -> all 16-24 loads concurrently in flight, one latency per
// pass (R3/R5 paid ~12 serialized uncached latencies per step due to regalloc recycling).
__global__ __launch_bounds__(256, 1)
void lstm_persist(const float* __restrict__ x,
                  const float* __restrict__ wii, const float* __restrict__ bii,
                  const float* __restrict__ wif_, const float* __restrict__ bif_,
                  const float* __restrict__ wig, const float* __restrict__ big_,
                  const float* __restrict__ wio, const float* __restrict__ bio,
                  const float* __restrict__ whi, const float* __restrict__ bhi,
                  const float* __restrict__ whf, const float* __restrict__ bhf,
                  const float* __restrict__ whg, const float* __restrict__ bhg,
                  const float* __restrict__ who, const float* __restrict__ bho,
                  float* __restrict__ out, uint8_t* __restrict__ ws)
{
  const int tid  = threadIdx.x;
  const int wid  = tid >> 6;      // wave 0..3 : K-split (K = 1536 = 512 x + 1024 h)
  const int lane = tid & 63;
  const int quad = lane >> 4;
  const int lrow = lane & 15;

  const int wg   = blockIdx.x;
  const int gb   = wg >> 6;       // batch group 0..3
  const int gc   = wg & 63;       // col group 0..63
  const int b0   = gb << 4;
  const int col0 = gc << 4;

  const float* wi[4] = {wii, wif_, wig, wio};
  const float* wh[4] = {whi, whf, whg, who};
  const float* bi[4] = {bii, bif_, big_, bio};
  const float* bh[4] = {bhi, bhf, bhg, bho};

  uint32_t* zg = (uint32_t*)ws + gb * (2 * 16 * HH);  // this group's tagged-h buffers

  // ---- persistent weight fragments (B operand: B[k][n], n=lane&15, k=quad*8+j) ----
  const int kb = wid * 384;       // this wave's K-range in concatenated K=[x(512); h(1024)]
  half8 wfrag[12][4];
#pragma unroll
  for (int kk = 0; kk < 12; ++kk) {
    const int k = kb + kk * 32 + quad * 8;
#pragma unroll
    for (int g = 0; g < 4; ++g) {
      const float* wp = (k < II) ? (wi[g] + (size_t)(col0 + lrow) * II + k)
                                 : (wh[g] + (size_t)(col0 + lrow) * HH + (k - II));
      half8 v;
#pragma unroll
      for (int j = 0; j < 8; ++j) v[j] = (_Float16)wp[j];
      wfrag[kk][g] = v;
    }
  }

  // per-thread elementwise ownership: (tb, thc) = one (batch, h-col) cell
  const int tb   = tid >> 4;
  const int thc  = tid & 15;
  const int gcol = col0 + thc;
  float bias[4];
#pragma unroll
  for (int g = 0; g < 4; ++g) bias[g] = bi[g][gcol] + bh[g][gcol];

  float c = 0.0f, h = 0.0f;

  __shared__ float red[2][16 * 288];  // double-buffered -> no end-of-step barrier

#pragma unroll 1
  for (int t = 0; t < TT; ++t) {
    const uint32_t* zp   = zg + (t & 1) * (16 * HH);
    uint32_t*       zn   = zg + ((t + 1) & 1) * (16 * HH);
    const float*    xrow = x + ((size_t)t * BB + b0 + lrow) * II;
    const uint32_t* zrow = zp + lrow * HH;

    // A frags: A[m=lane&15][k=quad*8+j]; k<512 from x (L2/L3-cached fp32)
    half8 af[12];
#pragma unroll
    for (int kk = 0; kk < 12; ++kk) {
      const int k = kb + kk * 32 + quad * 8;
      if (kb + kk * 32 < II) {
        f32x4 v0 = *(const f32x4*)(xrow + k);
        f32x4 v1 = *(const f32x4*)(xrow + k + 4);
        half8 v;
#pragma unroll
        for (int j = 0; j < 4; ++j) { v[j] = (_Float16)v0[j]; v[4 + j] = (_Float16)v1[j]; }
        af[kk] = v;
      }
    }

    // ---- h-part: batched tag-polled loads (one asm block = one latency per pass) ----
    if (t == 0) {
#pragma unroll
      for (int kk = 0; kk < 12; ++kk)
        if (kb + kk * 32 >= II) {
          half8 v;
#pragma unroll
          for (int j = 0; j < 8; ++j) v[j] = (_Float16)0.0f;
          af[kk] = v;
        }
    } else if (wid == 1) {        // 8 h-frags -> af[4..11]
      const uint32_t etag = 1u + ((t - 1) & 3u);
      const uint32_t* hb = zrow + quad * 8;
      u32x4 cw[16];
      int guard = 0;
      for (;;) {
        ZP8(cw, hb);
        uint32_t bad = 0u;
#pragma unroll
        for (int f = 0; f < 16; ++f)
#pragma unroll
          for (int j = 0; j < 4; ++j) bad |= (cw[f][j] ^ etag) & 7u;
        if (__all(bad == 0u)) break;
        if (++guard > (1 << 15)) break;              // fail loud, not hang
        __builtin_amdgcn_s_sleep(1);
      }
#pragma unroll
      for (int f = 0; f < 8; ++f) {
        half8 v;
#pragma unroll
        for (int j = 0; j < 4; ++j) {
          v[j]     = (_Float16)__uint_as_float(cw[2 * f][j]);      // tag: <=2^-20 rel noise
          v[4 + j] = (_Float16)__uint_as_float(cw[2 * f + 1][j]);
        }
        af[4 + f] = v;
      }
    } else if (wid >= 2) {        // 12 h-frags -> af[0..11]
      const uint32_t etag = 1u + ((t - 1) & 3u);
      const uint32_t* hb = zrow + (wid == 2 ? 256 : 640) + quad * 8;
      u32x4 cw[24];
      int guard = 0;
      for (;;) {
        ZP12(cw, hb);
        uint32_t bad = 0u;
#pragma unroll
        for (int f = 0; f < 24; ++f)
#pragma unroll
          for (int j = 0; j < 4; ++j) bad |= (cw[f][j] ^ etag) & 7u;
        if (__all(bad == 0u)) break;
        if (++guard > (1 << 15)) break;              // fail loud, not hang
        __builtin_amdgcn_s_sleep(1);
      }
#pragma unroll
      for (int f = 0; f < 12; ++f) {
        half8 v;
#pragma unroll
        for (int j = 0; j < 4; ++j) {
          v[j]     = (_Float16)__uint_as_float(cw[2 * f][j]);
          v[4 + j] = (_Float16)__uint_as_float(cw[2 * f + 1][j]);
        }
        af[f] = v;
      }
    }

    f32x4 acc[4];
#pragma unroll
    for (int g = 0; g < 4; ++g) acc[g] = (f32x4){0.f, 0.f, 0.f, 0.f};
#pragma unroll
    for (int kk = 0; kk < 12; ++kk)
#pragma unroll
      for (int g = 0; g < 4; ++g)
        acc[g] = __builtin_amdgcn_mfma_f32_16x16x32_f16(af[kk], wfrag[kk][g], acc[g], 0, 0, 0);

    // cross-wave K reduction via LDS; D layout: row(m)=quad*4+r, col(n)=lane&15
    float* redb = red[t & 1];
#pragma unroll
    for (int g = 0; g < 4; ++g)
#pragma unroll
      for (int r = 0; r < 4; ++r)
        redb[(wid * 4 + g) * 288 + quad * 72 + r * 16 + lrow] = acc[g][r];
    __syncthreads();   // only barrier per step; all outstanding vmem is a step old

    float pre[4];
#pragma unroll
    for (int g = 0; g < 4; ++g) {
      float s = bias[g];
#pragma unroll
      for (int w = 0; w < 4; ++w)
        s += redb[(w * 4 + g) * 288 + (tb >> 2) * 72 + (tb & 3) * 16 + thc];
      pre[g] = s;
    }

    const float it = fsig(pre[0]);
    const float ft = fsig(pre[1]);
    const float gt = ftanh(pre[2]);
    const float ot = fsig(pre[3]);
    c = ft * c + it * gt;
    h = ot * ftanh(c);

    // publish FIRST (starts the one-way L3 trip), then the HBM out-store.
    if (t < TT - 1) {
      const uint32_t stag = 1u + (t & 3u);
      __hip_atomic_store(zn + tb * HH + gcol, (__float_as_uint(h) & ~7u) | stag,
                         __ATOMIC_RELAXED, __HIP_MEMORY_SCOPE_AGENT);
    }
    out[((size_t)t * BB + b0 + tb) * HH + gcol] = h;
  }

  // tails: h_T then c_T, each [B][H]
  out[(size_t)TT * BB * HH + (size_t)(b0 + tb) * HH + gcol] = h;
  out[(size_t)TT * BB * HH + (size_t)BB * HH + (size_t)(b0 + tb) * HH + gcol] = c;
}

extern "C" void kernel_launch(void* const* d_in, const int* in_sizes, int n_in,
                              void* d_out, int out_size, void* d_ws, size_t ws_size,
                              hipStream_t stream) {
  const float* x    = (const float*)d_in[0];
  const float* wii  = (const float*)d_in[1];
  const float* bii  = (const float*)d_in[2];
  const float* wif_ = (const float*)d_in[3];
  const float* bif_ = (const float*)d_in[4];
  const float* wig  = (const float*)d_in[5];
  const float* big_ = (const float*)d_in[6];
  const float* wio  = (const float*)d_in[7];
  const float* bio  = (const float*)d_in[8];
  const float* whi  = (const float*)d_in[9];
  const float* bhi  = (const float*)d_in[10];
  const float* whf  = (const float*)d_in[11];
  const float* bhf  = (const float*)d_in[12];
  const float* whg  = (const float*)d_in[13];
  const float* bhg  = (const float*)d_in[14];
  const float* who  = (const float*)d_in[15];
  const float* bho  = (const float*)d_in[16];

  lstm_init<<<(ZWORDS + 255) / 256, 256, 0, stream>>>((uint32_t*)d_ws);
  lstm_persist<<<256, 256, 0, stream>>>(x, wii, bii, wif_, bif_, wig, big_, wio, bio,
                                        whi, bhi, whf, bhf, whg, bhg, who, bho,
                                        (float*)d_out, (uint8_t*)d_ws);
}